// Round 6
// baseline (288.507 us; speedup 1.0000x reference)
//
#include <hip/hip_runtime.h>
#include <math.h>

typedef unsigned short u16;
typedef unsigned int u32;

typedef __attribute__((ext_vector_type(8))) short bf16x8;
typedef __attribute__((ext_vector_type(4))) float f32x4;

__device__ __forceinline__ u16 f2bf(float f) {
  union { float f; u32 u; } v; v.f = f;
  u32 r = v.u + 0x7FFFu + ((v.u >> 16) & 1u);
  return (u16)(r >> 16);
}
__device__ __forceinline__ float bf2f(u16 h) {
  union { u32 u; float f; } v; v.u = ((u32)h) << 16; return v.f;
}

typedef const u32 __attribute__((address_space(1)))* gas1_t;
typedef u32 __attribute__((address_space(3)))* las3_t;

__device__ __forceinline__ void gload16(const void* g, void* l) {
  __builtin_amdgcn_global_load_lds((gas1_t)g, (las3_t)l, 16, 0, 0);
}

struct Tile { int kind; int g0; int n0; int e; };  // kind<0 => skip

// ---------------- prep: router (blocks 0..1023) + weight convert (rest) ------
__global__ __launch_bounds__(256) void prep_kernel(
    const float* __restrict__ x, const float* __restrict__ wr,
    u16* __restrict__ xb, int* __restrict__ tokE, float* __restrict__ tokW,
    const float4* __restrict__ w1, const float4* __restrict__ w2,
    const float4* __restrict__ s1, const float4* __restrict__ s2,
    ushort4* __restrict__ o1, ushort4* __restrict__ o2,
    ushort4* __restrict__ o3, ushort4* __restrict__ o4) {
  if (blockIdx.x >= 1024) {
    size_t i = (size_t)(blockIdx.x - 1024) * 256 + threadIdx.x;
    const size_t n1 = 2097152, n2 = 2097152, n3 = 524288;
    float4 v; ushort4* o; size_t j;
    if (i < n1)              { v = w1[i];            o = o1; j = i; }
    else if (i < n1+n2)      { v = w2[i-n1];         o = o2; j = i-n1; }
    else if (i < n1+n2+n3)   { v = s1[i-n1-n2];      o = o3; j = i-n1-n2; }
    else                     { v = s2[i-n1-n2-n3];   o = o4; j = i-n1-n2-n3; }
    ushort4 r; r.x = f2bf(v.x); r.y = f2bf(v.y); r.z = f2bf(v.z); r.w = f2bf(v.w);
    o[j] = r;
    return;
  }
  const int wv = threadIdx.x >> 6, lane = threadIdx.x & 63;
  const int tok = blockIdx.x * 4 + wv;
  const float4* xp = (const float4*)(x + (size_t)tok * 1024);
  float4 xv[4];
#pragma unroll
  for (int i = 0; i < 4; ++i) xv[i] = xp[i * 64 + lane];
  ushort4* xo = (ushort4*)xb + (size_t)tok * 256;
#pragma unroll
  for (int i = 0; i < 4; ++i) {
    ushort4 o;
    o.x = f2bf(xv[i].x); o.y = f2bf(xv[i].y); o.z = f2bf(xv[i].z); o.w = f2bf(xv[i].w);
    xo[i * 64 + lane] = o;
  }
  float acc[8];
#pragma unroll
  for (int e = 0; e < 8; ++e) acc[e] = 0.f;
#pragma unroll
  for (int e = 0; e < 8; ++e) {
    const float4* wp = (const float4*)(wr + e * 1024);
#pragma unroll
    for (int i = 0; i < 4; ++i) {
      float4 w4 = wp[i * 64 + lane];
      acc[e] += xv[i].x * w4.x + xv[i].y * w4.y + xv[i].z * w4.z + xv[i].w * w4.w;
    }
  }
#pragma unroll
  for (int m = 32; m > 0; m >>= 1)
#pragma unroll
    for (int e = 0; e < 8; ++e) acc[e] += __shfl_xor(acc[e], m, 64);
  if (lane == 0) {
    int e0 = 0;
#pragma unroll
    for (int e = 1; e < 8; ++e) if (acc[e] > acc[e0]) e0 = e;
    int e1 = (e0 == 0) ? 1 : 0;
#pragma unroll
    for (int e = 0; e < 8; ++e) if (e != e0 && acc[e] > acc[e1]) e1 = e;
    float p1 = __expf(acc[e1] - acc[e0]);
    float w1_ = p1 / (1.f + p1);
    float w0 = 1.f - w1_;
    tokE[tok * 2] = e0; tokE[tok * 2 + 1] = e1;
    tokW[tok * 2] = w0; tokW[tok * 2 + 1] = w1_;
  }
}

// ---------------- plan: hist + scan + assignment + XCD-aware tile tables -----
__global__ __launch_bounds__(256) void plan_kernel(
    const int* __restrict__ tokE, const float* __restrict__ tokW,
    Tile* __restrict__ upT, Tile* __restrict__ downT,
    int* __restrict__ rowtok, float* __restrict__ roww, int* __restrict__ invrow) {
  const int t = threadIdx.x, lane = t & 63, wv = t >> 6;
  int myE[32];
#pragma unroll
  for (int i = 0; i < 32; ++i) myE[i] = tokE[t * 32 + i];
  int lcnt[8] = {};
#pragma unroll
  for (int i = 0; i < 32; ++i) ++lcnt[myE[i]];

  __shared__ int wtot[8][4];
  __shared__ int aoffS[9];
  __shared__ int etile[72 * 2];   // per m-tile: expert (-1 pad), g0
  int excl[8];
#pragma unroll
  for (int e = 0; e < 8; ++e) {
    int v = lcnt[e];
#pragma unroll
    for (int off = 1; off < 64; off <<= 1) {
      int n = __shfl_up(v, (unsigned)off, 64);
      if (lane >= off) v += n;
    }
    if (lane == 63) wtot[e][wv] = v;
    excl[e] = v - lcnt[e];
  }
  __syncthreads();
#pragma unroll
  for (int e = 0; e < 8; ++e)
    for (int w = 0; w < wv; ++w) excl[e] += wtot[e][w];

  if (t == 0) {
    int s = 0, ti = 0;
    for (int e = 0; e < 8; ++e) {
      aoffS[e] = s;
      int cnt = wtot[e][0] + wtot[e][1] + wtot[e][2] + wtot[e][3];
      int tiles = (cnt + 127) >> 7;
      for (int k = 0; k < tiles; ++k) { etile[2 * ti] = e; etile[2 * ti + 1] = s + k * 128; ++ti; }
      s += tiles << 7;
    }
    aoffS[8] = s;
    for (; ti < 72; ++ti) { etile[2 * ti] = -1; etile[2 * ti + 1] = 0; }
  }
  for (int i = t; i < 9216; i += 256) { rowtok[i] = 0; roww[i] = 0.f; }
  __syncthreads();

  // ---- up table: 1088 = 8 XCD * (64 s1 slots + 72 m1 slots)
  for (int i = t; i < 1088; i += 256) {
    int x = i & 7, s = i >> 3;
    Tile tl;
    if (s < 64) {             // s1: 32g x 16n; region per XCD: 8g x 8n
      int gg = x & 3, nn = x >> 2;
      int gl = s & 7, nl = s >> 3;          // g fastest
      tl.kind = 0; tl.g0 = (gg * 8 + gl) * 128; tl.n0 = (nn * 8 + nl) * 128; tl.e = 0;
    } else {                  // m1: 72m x 8n; region per XCD: 18m x 4n
      int s2_ = s - 64;
      int mg = x & 3, ng = x >> 2;
      int ml = s2_ % 18, nl = s2_ / 18;     // m fastest
      int mi = mg * 18 + ml;
      int e = etile[2 * mi];
      tl.kind = (e < 0) ? -1 : 1; tl.g0 = etile[2 * mi + 1];
      tl.n0 = (ng * 4 + nl) * 128; tl.e = (e < 0) ? 0 : e;
    }
    upT[i] = tl;
  }
  // ---- down table: 832 = 8 XCD * (32 s2 slots + 72 m2 slots)
  for (int i = t; i < 832; i += 256) {
    int x = i & 7, s = i >> 3;
    Tile tl;
    if (s < 32) {             // s2: 32g x 8n; region per XCD: 8g x 4n
      int gg = x & 3, nn = x >> 2;
      int gl = s & 7, nl = s >> 3;          // g fastest
      tl.kind = 0; tl.g0 = (gg * 8 + gl) * 128; tl.n0 = (nn * 4 + nl) * 128; tl.e = 0;
    } else {                  // m2: 72m x 8n; region per XCD: 18m x 4n
      int s2_ = s - 32;
      int mg = x & 3, ng = x >> 2;
      int ml = s2_ % 18, nl = s2_ / 18;
      int mi = mg * 18 + ml;
      int e = etile[2 * mi];
      tl.kind = (e < 0) ? -1 : 1; tl.g0 = etile[2 * mi + 1];
      tl.n0 = (ng * 4 + nl) * 128; tl.e = (e < 0) ? 0 : e;
    }
    downT[i] = tl;
  }

  int pos[8];
#pragma unroll
  for (int e = 0; e < 8; ++e) pos[e] = aoffS[e] + excl[e];
#pragma unroll
  for (int i = 0; i < 32; ++i) {
    int idx = t * 32 + i;
    int e = myE[i];
    int g = pos[e]++;
    rowtok[g] = idx >> 1;
    roww[g] = tokW[idx];
    invrow[idx] = g;
  }
}

// ---------------- combine: out[t] += w0*Ym[r0] + w1*Ym[r1]  (Ym is bf16) -----
__global__ __launch_bounds__(256) void combine_kernel(
    const u16* __restrict__ Ym, const int* __restrict__ invrow,
    const float* __restrict__ tokW, float* __restrict__ out) {
  const int t = blockIdx.x;
  const int r0 = invrow[2 * t], r1 = invrow[2 * t + 1];
  const float w0 = tokW[2 * t], w1 = tokW[2 * t + 1];
  const ushort4* y0 = (const ushort4*)(Ym + (size_t)r0 * 1024);
  const ushort4* y1 = (const ushort4*)(Ym + (size_t)r1 * 1024);
  float4* o = (float4*)(out + (size_t)t * 1024);
  const int c = threadIdx.x;
  ushort4 a = y0[c], b = y1[c];
  float4 v = o[c];
  v.x += w0 * bf2f(a.x) + w1 * bf2f(b.x);
  v.y += w0 * bf2f(a.y) + w1 * bf2f(b.y);
  v.z += w0 * bf2f(a.z) + w1 * bf2f(b.z);
  v.w += w0 * bf2f(a.w) + w1 * bf2f(b.w);
  o[c] = v;
}

// ---------------- fused bf16 GEMM over tile table, 128x128, BK=32 ------------
// EXACT round-3 core (measured: 0 bank conflicts, 68 VGPR, full-128B-line
// staging): LDS 128x32 per matrix, swizzle chunk (row,q) -> slot (q+(row>>1))&3.
// PHASE 0: up   — kind0 s1 (N=2048,K=1024, sqrelu->bf16 Hs)
//                 kind1 m1 (gather, N=K=1024, sqrelu->bf16 Hm)
// PHASE 1: down — kind0 s2 (N=1024,K=2048, fp32 -> out)
//                 kind1 m2 (N=K=1024, bf16 -> Ym)
// PHASE 2/3: fallback split (fp32 out / weighted atomics)
template <int PHASE>
__global__ __launch_bounds__(256)
void gemm_fused(const Tile* __restrict__ tiles,
                const u16* __restrict__ A0, const u16* __restrict__ B0, void* __restrict__ C0,
                const u16* __restrict__ A1, const u16* __restrict__ B1, void* __restrict__ C1,
                const int* __restrict__ rowtok, const float* __restrict__ roww) {
  __shared__ u16 As[128 * 32];
  __shared__ u16 Bs[128 * 32];

  Tile tm = tiles[blockIdx.x];
  if (tm.kind < 0) return;
  if (PHASE == 2 && tm.kind != 0) return;
  if (PHASE == 3 && tm.kind != 1) return;

  const int tid = threadIdx.x;
  const int lane = tid & 63;
  const int wv = tid >> 6;
  const int wrow = wv >> 1, wcol = wv & 1;

  const u16* A; const u16* B; void* C; int N, K;
  if (tm.kind == 0) {
    A = A0; B = B0; C = C0;
    N = (PHASE == 0) ? 2048 : 1024;
    K = (PHASE == 0) ? 1024 : 2048;
  } else {
    A = A1; B = B1 + ((size_t)tm.e << 20); C = (PHASE == 3) ? C0 : C1;
    N = 1024; K = 1024;
  }
  const int g0 = tm.g0, n0 = tm.n0;

  const u16* aSrc[2];
  const u16* bSrc[2];
  u32 ldsOff[2];
#pragma unroll
  for (int p = 0; p < 2; ++p) {
    int c = p * 256 + tid;
    int row = c >> 2;
    int q = ((c & 3) - (c >> 3)) & 3;   // inverse of slot=(q+(row>>1))&3
    int arow = g0 + row;
    if (PHASE == 0 && tm.kind == 1) arow = rowtok[arow];
    aSrc[p] = A + (size_t)arow * K + q * 8;
    bSrc[p] = B + (size_t)(n0 + row) * K + q * 8;
    ldsOff[p] = (u32)(p * 256 + wv * 64) * 16u;  // wave-uniform byte base
  }

  const int fr = lane & 15, fq = lane >> 4;
  const int sw = ((fq + (fr >> 1)) & 3) * 8;     // measured-0-conflict swizzle
  const int aRd = (wrow * 64 + fr) * 32 + sw;
  const int bRd = (wcol * 64 + fr) * 32 + sw;

  f32x4 acc[4][4] = {};

  for (int k0 = 0; k0 < K; k0 += 32) {
#pragma unroll
    for (int p = 0; p < 2; ++p) {
      gload16(aSrc[p] + k0, (char*)As + ldsOff[p]);
      gload16(bSrc[p] + k0, (char*)Bs + ldsOff[p]);
    }
    __syncthreads();
    bf16x8 af[4], bfg[4];
#pragma unroll
    for (int i = 0; i < 4; ++i) af[i] = *(const bf16x8*)&As[aRd + i * 512];
#pragma unroll
    for (int j = 0; j < 4; ++j) bfg[j] = *(const bf16x8*)&Bs[bRd + j * 512];
#pragma unroll
    for (int i = 0; i < 4; ++i)
#pragma unroll
      for (int j = 0; j < 4; ++j)
        acc[i][j] = __builtin_amdgcn_mfma_f32_16x16x32_bf16(af[i], bfg[j], acc[i][j], 0, 0, 0);
    __syncthreads();
  }

  // C/D layout: col = lane&15, row = (lane>>4)*4 + reg
  if (PHASE == 0) {
    u16* O = (u16*)C;
#pragma unroll
    for (int i = 0; i < 4; ++i) {
      int rb = g0 + wrow * 64 + i * 16 + fq * 4;
#pragma unroll
      for (int j = 0; j < 4; ++j) {
        int col = n0 + wcol * 64 + j * 16 + fr;
#pragma unroll
        for (int r = 0; r < 4; ++r) {
          float v = acc[i][j][r];
          v = v > 0.f ? v * v : 0.f;
          O[(size_t)(rb + r) * N + col] = f2bf(v);
        }
      }
    }
  } else if (PHASE == 1) {
    if (tm.kind == 0) {
      float* O = (float*)C;
#pragma unroll
      for (int i = 0; i < 4; ++i) {
        int rb = g0 + wrow * 64 + i * 16 + fq * 4;
#pragma unroll
        for (int j = 0; j < 4; ++j) {
          int col = n0 + wcol * 64 + j * 16 + fr;
#pragma unroll
          for (int r = 0; r < 4; ++r)
            O[(size_t)(rb + r) * N + col] = acc[i][j][r];
        }
      }
    } else {
      u16* O = (u16*)C;
#pragma unroll
      for (int i = 0; i < 4; ++i) {
        int rb = g0 + wrow * 64 + i * 16 + fq * 4;
#pragma unroll
        for (int j = 0; j < 4; ++j) {
          int col = n0 + wcol * 64 + j * 16 + fr;
#pragma unroll
          for (int r = 0; r < 4; ++r)
            O[(size_t)(rb + r) * N + col] = f2bf(acc[i][j][r]);
        }
      }
    }
  } else if (PHASE == 2) {
    float* O = (float*)C;
#pragma unroll
    for (int i = 0; i < 4; ++i) {
      int rb = g0 + wrow * 64 + i * 16 + fq * 4;
#pragma unroll
      for (int j = 0; j < 4; ++j) {
        int col = n0 + wcol * 64 + j * 16 + fr;
#pragma unroll
        for (int r = 0; r < 4; ++r)
          O[(size_t)(rb + r) * N + col] = acc[i][j][r];
      }
    }
  } else {
    float* O = (float*)C;
#pragma unroll
    for (int i = 0; i < 4; ++i) {
      int rb = g0 + wrow * 64 + i * 16 + fq * 4;
#pragma unroll
      for (int r = 0; r < 4; ++r) {
        int tok = rowtok[rb + r];
        float w = roww[rb + r];
#pragma unroll
        for (int j = 0; j < 4; ++j) {
          int col = n0 + wcol * 64 + j * 16 + fr;
          atomicAdd(&O[(size_t)tok * N + col], w * acc[i][j][r]);
        }
      }
    }
  }
}

// ---------------- launch -----------------------------------------------------
extern "C" void kernel_launch(void* const* d_in, const int* in_sizes, int n_in,
                              void* d_out, int out_size, void* d_ws, size_t ws_size,
                              hipStream_t stream) {
  const float* x   = (const float*)d_in[0];
  const float* wr  = (const float*)d_in[1];
  const float* w1  = (const float*)d_in[2];
  const float* w2  = (const float*)d_in[3];
  const float* s1  = (const float*)d_in[4];
  const float* s2  = (const float*)d_in[5];
  float* out = (float*)d_out;

  char* p = (char*)d_ws;
  auto alloc = [&](size_t n) { char* r = p; p += (n + 255) & ~(size_t)255; return r; };
  u16* xb   = (u16*)alloc(4096ULL * 1024 * 2);
  u16* w1b  = (u16*)alloc(8ULL * 1024 * 1024 * 2);
  u16* w2b  = (u16*)alloc(8ULL * 1024 * 1024 * 2);
  u16* s1b  = (u16*)alloc(2048ULL * 1024 * 2);
  u16* s2b  = (u16*)alloc(1024ULL * 2048 * 2);
  u16* Hs   = (u16*)alloc(4096ULL * 2048 * 2);
  u16* Hm   = (u16*)alloc(9216ULL * 1024 * 2);
  int* tokE = (int*)alloc(8192 * 4);
  float* tokW = (float*)alloc(8192 * 4);
  int* rowtok = (int*)alloc(9216 * 4);
  float* roww = (float*)alloc(9216 * 4);
  int* invrow = (int*)alloc(8192 * 4);
  Tile* upT   = (Tile*)alloc(1088 * sizeof(Tile));
  Tile* downT = (Tile*)alloc(832 * sizeof(Tile));
  size_t used_base = (size_t)(p - (char*)d_ws);
  u16* Ym = (u16*)p;                              // 9216 x 1024 bf16 (18.9 MB)
  const bool haveYm = (ws_size - used_base) >= 9216ULL * 1024 * 2;

  prep_kernel<<<21504, 256, 0, stream>>>(
      x, wr, xb, tokE, tokW,
      (const float4*)w1, (const float4*)w2, (const float4*)s1, (const float4*)s2,
      (ushort4*)w1b, (ushort4*)w2b, (ushort4*)s1b, (ushort4*)s2b);

  plan_kernel<<<1, 256, 0, stream>>>(tokE, tokW, upT, downT, rowtok, roww, invrow);

  // up: s1 (xb->Hs) + m1 (gather(xb)->Hm), sqrelu->bf16
  gemm_fused<0><<<1088, 256, 0, stream>>>(upT, xb, s1b, Hs, xb, w1b, Hm, rowtok, roww);

  if (haveYm) {
    // down: s2 (Hs->out fp32) + m2 (Hm->Ym bf16); then combine
    gemm_fused<1><<<832, 256, 0, stream>>>(downT, Hs, s2b, out, Hm, w2b, Ym, rowtok, roww);
    combine_kernel<<<4096, 256, 0, stream>>>(Ym, invrow, tokW, out);
  } else {
    gemm_fused<2><<<832, 256, 0, stream>>>(downT, Hs, s2b, out, Hm, w2b, nullptr, rowtok, roww);
    gemm_fused<3><<<832, 256, 0, stream>>>(downT, Hs, s2b, out, Hm, w2b, nullptr, rowtok, roww);
  }
}

// Round 7
// 278.123 us; speedup vs baseline: 1.0373x; 1.0373x over previous
//
#include <hip/hip_runtime.h>
#include <math.h>

typedef unsigned short u16;
typedef unsigned int u32;

typedef __attribute__((ext_vector_type(8))) short bf16x8;
typedef __attribute__((ext_vector_type(4))) float f32x4;

__device__ __forceinline__ u16 f2bf(float f) {
  union { float f; u32 u; } v; v.f = f;
  u32 r = v.u + 0x7FFFu + ((v.u >> 16) & 1u);
  return (u16)(r >> 16);
}
__device__ __forceinline__ float bf2f(u16 h) {
  union { u32 u; float f; } v; v.u = ((u32)h) << 16; return v.f;
}

typedef const u32 __attribute__((address_space(1)))* gas1_t;
typedef u32 __attribute__((address_space(3)))* las3_t;

__device__ __forceinline__ void gload16(const void* g, void* l) {
  __builtin_amdgcn_global_load_lds((gas1_t)g, (las3_t)l, 16, 0, 0);
}

struct Tile { int kind; int g0; int n0; int e; };  // kind<0 => skip

// ---------------- prep: router (blocks 0..1023) + weight convert (rest) ------
__global__ __launch_bounds__(256) void prep_kernel(
    const float* __restrict__ x, const float* __restrict__ wr,
    u16* __restrict__ xb, int* __restrict__ tokE, float* __restrict__ tokW,
    const float4* __restrict__ w1, const float4* __restrict__ w2,
    const float4* __restrict__ s1, const float4* __restrict__ s2,
    ushort4* __restrict__ o1, ushort4* __restrict__ o2,
    ushort4* __restrict__ o3, ushort4* __restrict__ o4) {
  if (blockIdx.x >= 1024) {
    size_t i = (size_t)(blockIdx.x - 1024) * 256 + threadIdx.x;
    const size_t n1 = 2097152, n2 = 2097152, n3 = 524288;
    float4 v; ushort4* o; size_t j;
    if (i < n1)              { v = w1[i];            o = o1; j = i; }
    else if (i < n1+n2)      { v = w2[i-n1];         o = o2; j = i-n1; }
    else if (i < n1+n2+n3)   { v = s1[i-n1-n2];      o = o3; j = i-n1-n2; }
    else                     { v = s2[i-n1-n2-n3];   o = o4; j = i-n1-n2-n3; }
    ushort4 r; r.x = f2bf(v.x); r.y = f2bf(v.y); r.z = f2bf(v.z); r.w = f2bf(v.w);
    o[j] = r;
    return;
  }
  const int wv = threadIdx.x >> 6, lane = threadIdx.x & 63;
  const int tok = blockIdx.x * 4 + wv;
  const float4* xp = (const float4*)(x + (size_t)tok * 1024);
  float4 xv[4];
#pragma unroll
  for (int i = 0; i < 4; ++i) xv[i] = xp[i * 64 + lane];
  ushort4* xo = (ushort4*)xb + (size_t)tok * 256;
#pragma unroll
  for (int i = 0; i < 4; ++i) {
    ushort4 o;
    o.x = f2bf(xv[i].x); o.y = f2bf(xv[i].y); o.z = f2bf(xv[i].z); o.w = f2bf(xv[i].w);
    xo[i * 64 + lane] = o;
  }
  float acc[8];
#pragma unroll
  for (int e = 0; e < 8; ++e) acc[e] = 0.f;
#pragma unroll
  for (int e = 0; e < 8; ++e) {
    const float4* wp = (const float4*)(wr + e * 1024);
#pragma unroll
    for (int i = 0; i < 4; ++i) {
      float4 w4 = wp[i * 64 + lane];
      acc[e] += xv[i].x * w4.x + xv[i].y * w4.y + xv[i].z * w4.z + xv[i].w * w4.w;
    }
  }
#pragma unroll
  for (int m = 32; m > 0; m >>= 1)
#pragma unroll
    for (int e = 0; e < 8; ++e) acc[e] += __shfl_xor(acc[e], m, 64);
  if (lane == 0) {
    int e0 = 0;
#pragma unroll
    for (int e = 1; e < 8; ++e) if (acc[e] > acc[e0]) e0 = e;
    int e1 = (e0 == 0) ? 1 : 0;
#pragma unroll
    for (int e = 0; e < 8; ++e) if (e != e0 && acc[e] > acc[e1]) e1 = e;
    float p1 = __expf(acc[e1] - acc[e0]);
    float w1_ = p1 / (1.f + p1);
    float w0 = 1.f - w1_;
    tokE[tok * 2] = e0; tokE[tok * 2 + 1] = e1;
    tokW[tok * 2] = w0; tokW[tok * 2 + 1] = w1_;
  }
}

// ---------------- plan: hist + scan + assignment + XCD-aware tile tables -----
__global__ __launch_bounds__(256) void plan_kernel(
    const int* __restrict__ tokE, const float* __restrict__ tokW,
    Tile* __restrict__ upT, Tile* __restrict__ downT,
    int* __restrict__ rowtok, float* __restrict__ roww, int* __restrict__ invrow) {
  const int t = threadIdx.x, lane = t & 63, wv = t >> 6;
  int myE[32];
#pragma unroll
  for (int i = 0; i < 32; ++i) myE[i] = tokE[t * 32 + i];
  int lcnt[8] = {};
#pragma unroll
  for (int i = 0; i < 32; ++i) ++lcnt[myE[i]];

  __shared__ int wtot[8][4];
  __shared__ int aoffS[9];
  __shared__ int etile[72 * 2];   // per m-tile: expert (-1 pad), g0
  int excl[8];
#pragma unroll
  for (int e = 0; e < 8; ++e) {
    int v = lcnt[e];
#pragma unroll
    for (int off = 1; off < 64; off <<= 1) {
      int n = __shfl_up(v, (unsigned)off, 64);
      if (lane >= off) v += n;
    }
    if (lane == 63) wtot[e][wv] = v;
    excl[e] = v - lcnt[e];
  }
  __syncthreads();
#pragma unroll
  for (int e = 0; e < 8; ++e)
    for (int w = 0; w < wv; ++w) excl[e] += wtot[e][w];

  if (t == 0) {
    int s = 0, ti = 0;
    for (int e = 0; e < 8; ++e) {
      aoffS[e] = s;
      int cnt = wtot[e][0] + wtot[e][1] + wtot[e][2] + wtot[e][3];
      int tiles = (cnt + 127) >> 7;
      for (int k = 0; k < tiles; ++k) { etile[2 * ti] = e; etile[2 * ti + 1] = s + k * 128; ++ti; }
      s += tiles << 7;
    }
    aoffS[8] = s;
    for (; ti < 72; ++ti) { etile[2 * ti] = -1; etile[2 * ti + 1] = 0; }
  }
  for (int i = t; i < 9216; i += 256) { rowtok[i] = 0; roww[i] = 0.f; }
  __syncthreads();

  // ---- up table: 1088 = 8 XCD * (64 s1 slots + 72 m1 slots)
  for (int i = t; i < 1088; i += 256) {
    int x = i & 7, s = i >> 3;
    Tile tl;
    if (s < 64) {             // s1: 32g x 16n; region per XCD: 8g x 8n
      int gg = x & 3, nn = x >> 2;
      int gl = s & 7, nl = s >> 3;          // g fastest
      tl.kind = 0; tl.g0 = (gg * 8 + gl) * 128; tl.n0 = (nn * 8 + nl) * 128; tl.e = 0;
    } else {                  // m1: 72m x 8n; region per XCD: 18m x 4n
      int s2_ = s - 64;
      int mg = x & 3, ng = x >> 2;
      int ml = s2_ % 18, nl = s2_ / 18;     // m fastest
      int mi = mg * 18 + ml;
      int e = etile[2 * mi];
      tl.kind = (e < 0) ? -1 : 1; tl.g0 = etile[2 * mi + 1];
      tl.n0 = (ng * 4 + nl) * 128; tl.e = (e < 0) ? 0 : e;
    }
    upT[i] = tl;
  }
  // ---- down table: 832 = 8 XCD * (32 s2 slots + 72 m2 slots)
  for (int i = t; i < 832; i += 256) {
    int x = i & 7, s = i >> 3;
    Tile tl;
    if (s < 32) {             // s2: 32g x 8n; region per XCD: 8g x 4n
      int gg = x & 3, nn = x >> 2;
      int gl = s & 7, nl = s >> 3;          // g fastest
      tl.kind = 0; tl.g0 = (gg * 8 + gl) * 128; tl.n0 = (nn * 4 + nl) * 128; tl.e = 0;
    } else {                  // m2: 72m x 8n; region per XCD: 18m x 4n
      int s2_ = s - 32;
      int mg = x & 3, ng = x >> 2;
      int ml = s2_ % 18, nl = s2_ / 18;
      int mi = mg * 18 + ml;
      int e = etile[2 * mi];
      tl.kind = (e < 0) ? -1 : 1; tl.g0 = etile[2 * mi + 1];
      tl.n0 = (ng * 4 + nl) * 128; tl.e = (e < 0) ? 0 : e;
    }
    downT[i] = tl;
  }

  int pos[8];
#pragma unroll
  for (int e = 0; e < 8; ++e) pos[e] = aoffS[e] + excl[e];
#pragma unroll
  for (int i = 0; i < 32; ++i) {
    int idx = t * 32 + i;
    int e = myE[i];
    int g = pos[e]++;
    rowtok[g] = idx >> 1;
    roww[g] = tokW[idx];
    invrow[idx] = g;
  }
}

// ---------------- combine: out[t] += w0*Ym[r0] + w1*Ym[r1]  (Ym is bf16) -----
__global__ __launch_bounds__(256) void combine_kernel(
    const u16* __restrict__ Ym, const int* __restrict__ invrow,
    const float* __restrict__ tokW, float* __restrict__ out) {
  const int t = blockIdx.x;
  const int r0 = invrow[2 * t], r1 = invrow[2 * t + 1];
  const float w0 = tokW[2 * t], w1 = tokW[2 * t + 1];
  const ushort4* y0 = (const ushort4*)(Ym + (size_t)r0 * 1024);
  const ushort4* y1 = (const ushort4*)(Ym + (size_t)r1 * 1024);
  float4* o = (float4*)(out + (size_t)t * 1024);
  const int c = threadIdx.x;
  ushort4 a = y0[c], b = y1[c];
  float4 v = o[c];
  v.x += w0 * bf2f(a.x) + w1 * bf2f(b.x);
  v.y += w0 * bf2f(a.y) + w1 * bf2f(b.y);
  v.z += w0 * bf2f(a.z) + w1 * bf2f(b.z);
  v.w += w0 * bf2f(a.w) + w1 * bf2f(b.w);
  o[c] = v;
}

// ---------------- fused bf16 GEMM over tile table, 128x128, BK=64 ------------
// R4-style FULL-LINE staging (each wave's global_load_lds covers 8 complete
// 128 B cache lines), rotation swizzle: chunk (row,q) at slot (q+row)&7 within
// the 128 B LDS row. Read slot for k-chunk c: (c+fr)&7 -> every 8-lane phase
// covers all 8 slots; 16-lane phase = exact 2 lanes/bank.
// PHASE 0: up   — kind0 s1 (N=2048,K=1024, sqrelu->bf16 Hs)
//                 kind1 m1 (gather, N=K=1024, sqrelu->bf16 Hm)
// PHASE 1: down — kind0 s2 (N=1024,K=2048, fp32 -> out)
//                 kind1 m2 (N=K=1024, bf16 -> Ym)
// PHASE 2/3: fallback split (fp32 out / weighted atomics)
template <int PHASE>
__global__ __launch_bounds__(256)
void gemm_fused(const Tile* __restrict__ tiles,
                const u16* __restrict__ A0, const u16* __restrict__ B0, void* __restrict__ C0,
                const u16* __restrict__ A1, const u16* __restrict__ B1, void* __restrict__ C1,
                const int* __restrict__ rowtok, const float* __restrict__ roww) {
  __shared__ u16 As[128 * 64];
  __shared__ u16 Bs[128 * 64];

  Tile tm = tiles[blockIdx.x];
  if (tm.kind < 0) return;
  if (PHASE == 2 && tm.kind != 0) return;
  if (PHASE == 3 && tm.kind != 1) return;

  const int tid = threadIdx.x;
  const int lane = tid & 63;
  const int wv = tid >> 6;
  const int wrow = wv >> 1, wcol = wv & 1;

  const u16* A; const u16* B; void* C; int N, K;
  if (tm.kind == 0) {
    A = A0; B = B0; C = C0;
    N = (PHASE == 0) ? 2048 : 1024;
    K = (PHASE == 0) ? 1024 : 2048;
  } else {
    A = A1; B = B1 + ((size_t)tm.e << 20); C = (PHASE == 3) ? C0 : C1;
    N = 1024; K = 1024;
  }
  const int g0 = tm.g0, n0 = tm.n0;

  // staging: chunk c = p*256+tid; row=c>>3, slot=c&7, source q=(slot-row)&7.
  // wave covers 8 rows x all 8 slots -> 8 full 128 B lines per instruction.
  const u16* aSrc[4];
  const u16* bSrc[4];
#pragma unroll
  for (int p = 0; p < 4; ++p) {
    int c = p * 256 + tid;
    int row = c >> 3;
    int q = ((c & 7) - row) & 7;
    int arow = g0 + row;
    if (PHASE == 0 && tm.kind == 1) arow = rowtok[arow];
    aSrc[p] = A + (size_t)arow * K + q * 8;
    bSrc[p] = B + (size_t)(n0 + row) * K + q * 8;
  }
  const u32 ldsW = (u32)(wv * 64) * 16u;   // wave-uniform byte base (per p: +4096)

  const int fr = lane & 15, fq = lane >> 4;
  const int sw0 = ((fq + fr) & 7) * 8;       // k-chunks 0..3 (ks=0)
  const int sw1 = ((fq + 4 + fr) & 7) * 8;   // k-chunks 4..7 (ks=1)
  const int aRow = (wrow * 64 + fr) * 64;
  const int bRow = (wcol * 64 + fr) * 64;

  f32x4 acc[4][4] = {};

  for (int k0 = 0; k0 < K; k0 += 64) {
#pragma unroll
    for (int p = 0; p < 4; ++p) {
      gload16(aSrc[p] + k0, (char*)As + ldsW + p * 4096);
      gload16(bSrc[p] + k0, (char*)Bs + ldsW + p * 4096);
    }
    __syncthreads();
#pragma unroll
    for (int ks = 0; ks < 2; ++ks) {
      const int sw = ks ? sw1 : sw0;
      bf16x8 af[4], bfg[4];
#pragma unroll
      for (int i = 0; i < 4; ++i) af[i] = *(const bf16x8*)&As[aRow + i * 1024 + sw];
#pragma unroll
      for (int j = 0; j < 4; ++j) bfg[j] = *(const bf16x8*)&Bs[bRow + j * 1024 + sw];
#pragma unroll
      for (int i = 0; i < 4; ++i)
#pragma unroll
        for (int j = 0; j < 4; ++j)
          acc[i][j] = __builtin_amdgcn_mfma_f32_16x16x32_bf16(af[i], bfg[j], acc[i][j], 0, 0, 0);
    }
    __syncthreads();
  }

  // C/D layout: col = lane&15, row = (lane>>4)*4 + reg
  if (PHASE == 0) {
    u16* O = (u16*)C;
#pragma unroll
    for (int i = 0; i < 4; ++i) {
      int rb = g0 + wrow * 64 + i * 16 + fq * 4;
#pragma unroll
      for (int j = 0; j < 4; ++j) {
        int col = n0 + wcol * 64 + j * 16 + fr;
#pragma unroll
        for (int r = 0; r < 4; ++r) {
          float v = acc[i][j][r];
          v = v > 0.f ? v * v : 0.f;
          O[(size_t)(rb + r) * N + col] = f2bf(v);
        }
      }
    }
  } else if (PHASE == 1) {
    if (tm.kind == 0) {
      float* O = (float*)C;
#pragma unroll
      for (int i = 0; i < 4; ++i) {
        int rb = g0 + wrow * 64 + i * 16 + fq * 4;
#pragma unroll
        for (int j = 0; j < 4; ++j) {
          int col = n0 + wcol * 64 + j * 16 + fr;
#pragma unroll
          for (int r = 0; r < 4; ++r)
            O[(size_t)(rb + r) * N + col] = acc[i][j][r];
        }
      }
    } else {
      u16* O = (u16*)C;
#pragma unroll
      for (int i = 0; i < 4; ++i) {
        int rb = g0 + wrow * 64 + i * 16 + fq * 4;
#pragma unroll
        for (int j = 0; j < 4; ++j) {
          int col = n0 + wcol * 64 + j * 16 + fr;
#pragma unroll
          for (int r = 0; r < 4; ++r)
            O[(size_t)(rb + r) * N + col] = f2bf(acc[i][j][r]);
        }
      }
    }
  } else if (PHASE == 2) {
    float* O = (float*)C;
#pragma unroll
    for (int i = 0; i < 4; ++i) {
      int rb = g0 + wrow * 64 + i * 16 + fq * 4;
#pragma unroll
      for (int j = 0; j < 4; ++j) {
        int col = n0 + wcol * 64 + j * 16 + fr;
#pragma unroll
        for (int r = 0; r < 4; ++r)
          O[(size_t)(rb + r) * N + col] = acc[i][j][r];
      }
    }
  } else {
    float* O = (float*)C;
#pragma unroll
    for (int i = 0; i < 4; ++i) {
      int rb = g0 + wrow * 64 + i * 16 + fq * 4;
#pragma unroll
      for (int r = 0; r < 4; ++r) {
        int tok = rowtok[rb + r];
        float w = roww[rb + r];
#pragma unroll
        for (int j = 0; j < 4; ++j) {
          int col = n0 + wcol * 64 + j * 16 + fr;
          atomicAdd(&O[(size_t)tok * N + col], w * acc[i][j][r]);
        }
      }
    }
  }
}

// ---------------- launch -----------------------------------------------------
extern "C" void kernel_launch(void* const* d_in, const int* in_sizes, int n_in,
                              void* d_out, int out_size, void* d_ws, size_t ws_size,
                              hipStream_t stream) {
  const float* x   = (const float*)d_in[0];
  const float* wr  = (const float*)d_in[1];
  const float* w1  = (const float*)d_in[2];
  const float* w2  = (const float*)d_in[3];
  const float* s1  = (const float*)d_in[4];
  const float* s2  = (const float*)d_in[5];
  float* out = (float*)d_out;

  char* p = (char*)d_ws;
  auto alloc = [&](size_t n) { char* r = p; p += (n + 255) & ~(size_t)255; return r; };
  u16* xb   = (u16*)alloc(4096ULL * 1024 * 2);
  u16* w1b  = (u16*)alloc(8ULL * 1024 * 1024 * 2);
  u16* w2b  = (u16*)alloc(8ULL * 1024 * 1024 * 2);
  u16* s1b  = (u16*)alloc(2048ULL * 1024 * 2);
  u16* s2b  = (u16*)alloc(1024ULL * 2048 * 2);
  u16* Hs   = (u16*)alloc(4096ULL * 2048 * 2);
  u16* Hm   = (u16*)alloc(9216ULL * 1024 * 2);
  int* tokE = (int*)alloc(8192 * 4);
  float* tokW = (float*)alloc(8192 * 4);
  int* rowtok = (int*)alloc(9216 * 4);
  float* roww = (float*)alloc(9216 * 4);
  int* invrow = (int*)alloc(8192 * 4);
  Tile* upT   = (Tile*)alloc(1088 * sizeof(Tile));
  Tile* downT = (Tile*)alloc(832 * sizeof(Tile));
  size_t used_base = (size_t)(p - (char*)d_ws);
  u16* Ym = (u16*)p;                              // 9216 x 1024 bf16 (18.9 MB)
  const bool haveYm = (ws_size - used_base) >= 9216ULL * 1024 * 2;

  prep_kernel<<<21504, 256, 0, stream>>>(
      x, wr, xb, tokE, tokW,
      (const float4*)w1, (const float4*)w2, (const float4*)s1, (const float4*)s2,
      (ushort4*)w1b, (ushort4*)w2b, (ushort4*)s1b, (ushort4*)s2b);

  plan_kernel<<<1, 256, 0, stream>>>(tokE, tokW, upT, downT, rowtok, roww, invrow);

  // up: s1 (xb->Hs) + m1 (gather(xb)->Hm), sqrelu->bf16
  gemm_fused<0><<<1088, 256, 0, stream>>>(upT, xb, s1b, Hs, xb, w1b, Hm, rowtok, roww);

  if (haveYm) {
    // down: s2 (Hs->out fp32) + m2 (Hm->Ym bf16); then combine
    gemm_fused<1><<<832, 256, 0, stream>>>(downT, Hs, s2b, out, Hm, w2b, Ym, rowtok, roww);
    combine_kernel<<<4096, 256, 0, stream>>>(Ym, invrow, tokW, out);
  } else {
    gemm_fused<2><<<832, 256, 0, stream>>>(downT, Hs, s2b, out, Hm, w2b, nullptr, rowtok, roww);
    gemm_fused<3><<<832, 256, 0, stream>>>(downT, Hs, s2b, out, Hm, w2b, nullptr, rowtok, roww);
  }
}